// Round 6
// baseline (218.396 us; speedup 1.0000x reference)
//
#include <hip/hip_runtime.h>
#include <cstddef>

#define NUM_BLOCKS 8
#define BLK 512
#define D_IN 2048
#define NROWS 8192
#define NBUCKETS (NUM_BLOCKS * BLK) /* 4096 */
#define CAP 32                      /* int-ELL padded capacity (tail path) */
#define NCHMAX (CAP / 4)
#define ROWS_PER_WG 4
#define THREADS 512
#define NBUK 8                      /* buckets per thread */
#define NT 4                        /* row-tiles per WG */
#define NWG (NROWS / ROWS_PER_WG / NT) /* 512 */
#define XS_ROWS 2052                /* 2048 + sentinel rows */
#define SENT_ENT (D_IN << 1)        /* sentinel: d=2048, sign + */

// Build inverted index: one WAVE per bucket. Ballot-match, ascending-d
// placement via popcount prefix. Outputs:
//  - entries16[bucket][8]: packed ushort ELL (first 8 entries, sentinel-pad)
//  - entries[bucket][CAP]: int ELL (full, sentinel-padded to 4) for tails
//  - nchunks[bucket]: total int4 chunks (tail runs chunks 2..nch)
__global__ __launch_bounds__(256) void cs_build_index(
    const int* __restrict__ i_hash, const float* __restrict__ s_hash,
    int* __restrict__ nchunks, int* __restrict__ entries,
    unsigned short* __restrict__ entries16)
{
    const int gid  = blockIdx.x * blockDim.x + threadIdx.x;
    const int wave = gid >> 6;            // bucket id
    const int lane = threadIdx.x & 63;
    if (wave >= NBUCKETS) return;
    const int b = wave >> 9;
    const int k = wave & (BLK - 1);
    const int*   ih = i_hash + b * D_IN;
    const float* sr = s_hash + b * D_IN;
    int* erow = entries + wave * CAP;
    unsigned short* e16 = entries16 + wave * 8;
    int cnt = 0;
    for (int d0 = 0; d0 < D_IN; d0 += 64) {
        const int d = d0 + lane;
        const bool m = (ih[d] == k);
        const unsigned long long mask = __ballot(m);
        if (m) {
            const int pos = cnt + __popcll(mask & ((1ull << lane) - 1ull));
            const int ent = (d << 1) | ((sr[d] < 0.0f) ? 1 : 0);
            if (pos < CAP) erow[pos] = ent;
            if (pos < 8)   e16[pos]  = (unsigned short)ent;
        }
        cnt += (int)__popcll(mask);
    }
    if (cnt > CAP) cnt = CAP;
    int nch = (cnt + 3) >> 2;
    if (nch == 0) nch = 1;
    if (lane >= cnt) {
        if (lane < 8)       e16[lane]  = (unsigned short)SENT_ENT;
        if (lane < nch * 4) erow[lane] = SENT_ENT;
    }
    if (lane == 0) nchunks[wave] = nch;
}

// Gather: per-WG register-resident entry table (8 buckets x 8 packed
// entries, one coalesced uint4 load each), double-buffered transposed x
// tile in LDS (xs[buf][d][4 rows], one ds_read_b128 serves 4 rows), 4
// tiles per WG with next-tile loads issued before compute. Fixed 8-entry
// branch-free unroll per bucket; rare cnt>8 tail from int-ELL (L2).
__global__ __launch_bounds__(THREADS, 4) void cs_gather(
    const float* __restrict__ x, const int* __restrict__ nchunks,
    const int* __restrict__ entries, const uint4* __restrict__ entries16,
    float* __restrict__ out)
{
    __shared__ float xs[2][XS_ROWS][4]; // 65.7 KiB -> 2 WGs/CU
    const int tid = threadIdx.x;
    const int row_base = blockIdx.x * (ROWS_PER_WG * NT);

    // Load per-thread bucket descriptors ONCE (coalesced 16B each).
    uint4 e8[NBUK];
    int   nch[NBUK];
#pragma unroll
    for (int jj = 0; jj < NBUK; ++jj) {
        const int j = jj * THREADS + tid;
        e8[jj]  = entries16[j];
        nch[jj] = nchunks[j];
    }

    // Zero sentinel rows of both buffers (d = 2048..2051).
    if (tid < 2 * (XS_ROWS - D_IN)) {
        const int buf = tid >> 2;
        *(float4*)&xs[buf][D_IN + (tid & 3)][0] = make_float4(0.f, 0.f, 0.f, 0.f);
    }

    // Stage tile 0 (transposed: 4 coalesced dword loads -> 1 b128 write).
    {
        const size_t b0 = (size_t)row_base * D_IN;
#pragma unroll
        for (int i = 0; i < 4; ++i) {
            const int d = tid + i * THREADS;
            float4 w;
            w.x = x[b0 + d];
            w.y = x[b0 + D_IN + d];
            w.z = x[b0 + 2 * D_IN + d];
            w.w = x[b0 + 3 * D_IN + d];
            *(float4*)&xs[0][d][0] = w;
        }
    }
    __syncthreads();

    const float scale = 0.35355339059327373f; // 1/sqrt(8)

#define PROC(e)                                                           \
    do {                                                                  \
        const int off = (((int)(e)) >> 1) << 4;                           \
        const float4 v = *(const float4*)((const char*)&X[0][0] + off);   \
        const float sg = ((e) & 1) ? -1.0f : 1.0f;                        \
        a0 = fmaf(sg, v.x, a0);                                           \
        a1 = fmaf(sg, v.y, a1);                                           \
        a2 = fmaf(sg, v.z, a2);                                           \
        a3 = fmaf(sg, v.w, a3);                                           \
    } while (0)

#pragma unroll 1
    for (int t = 0; t < NT; ++t) {
        const int cur = t & 1;
        const float (*X)[4] = xs[cur];

        // Issue next tile's global loads BEFORE compute (latency hides).
        float st[4][4];
        if (t + 1 < NT) {
            const size_t bn = (size_t)(row_base + (t + 1) * ROWS_PER_WG) * D_IN;
#pragma unroll
            for (int i = 0; i < 4; ++i) {
                const int d = tid + i * THREADS;
                st[i][0] = x[bn + d];
                st[i][1] = x[bn + D_IN + d];
                st[i][2] = x[bn + 2 * D_IN + d];
                st[i][3] = x[bn + 3 * D_IN + d];
            }
        }

        const int row0 = row_base + t * ROWS_PER_WG;
#pragma unroll
        for (int jj = 0; jj < NBUK; ++jj) {
            const int j = jj * THREADS + tid;
            float a0 = 0.f, a1 = 0.f, a2 = 0.f, a3 = 0.f;
            const uint4 ew = e8[jj];
            PROC(ew.x & 0xffffu); PROC(ew.x >> 16);
            PROC(ew.y & 0xffffu); PROC(ew.y >> 16);
            PROC(ew.z & 0xffffu); PROC(ew.z >> 16);
            PROC(ew.w & 0xffffu); PROC(ew.w >> 16);
            const int n = nch[jj];
            if (n > 2) {                       // rare (~2% of buckets)
                const int4* __restrict__ ep = (const int4*)(entries + j * CAP);
#pragma unroll 1
                for (int c = 2; c < n; ++c) {
                    const int4 cc = ep[c];
                    PROC(cc.x); PROC(cc.y); PROC(cc.z); PROC(cc.w);
                }
            }
            const size_t o = (size_t)row0 * NBUCKETS + j; // coalesced NT
            __builtin_nontemporal_store(a0 * scale, &out[o]);
            __builtin_nontemporal_store(a1 * scale, &out[o + NBUCKETS]);
            __builtin_nontemporal_store(a2 * scale, &out[o + 2 * NBUCKETS]);
            __builtin_nontemporal_store(a3 * scale, &out[o + 3 * NBUCKETS]);
        }

        // Write next tile into the other buffer; one barrier per tile.
        if (t + 1 < NT) {
#pragma unroll
            for (int i = 0; i < 4; ++i) {
                const int d = tid + i * THREADS;
                *(float4*)&xs[cur ^ 1][d][0] =
                    make_float4(st[i][0], st[i][1], st[i][2], st[i][3]);
            }
        }
        __syncthreads();
    }
#undef PROC
}

extern "C" void kernel_launch(void* const* d_in, const int* in_sizes, int n_in,
                              void* d_out, int out_size, void* d_ws, size_t ws_size,
                              hipStream_t stream)
{
    const float* x      = (const float*)d_in[0];
    const float* s_hash = (const float*)d_in[1];
    const int*   i_hash = (const int*)d_in[2];
    float* out = (float*)d_out;

    // ws: nchunks[4096] (16KB) | entries[4096][32] (512KB) | entries16 (64KB)
    int* nchunks = (int*)d_ws;
    int* entries = nchunks + NBUCKETS;
    unsigned short* entries16 = (unsigned short*)(entries + NBUCKETS * CAP);

    cs_build_index<<<(NBUCKETS * 64) / 256, 256, 0, stream>>>(
        i_hash, s_hash, nchunks, entries, entries16);
    cs_gather<<<NWG, THREADS, 0, stream>>>(
        x, nchunks, entries, (const uint4*)entries16, out);
}

// Round 7
// 55.571 us; speedup vs baseline: 3.9301x; 3.9301x over previous
//
#include <hip/hip_runtime.h>
#include <cstddef>

#define NUM_BLOCKS 8
#define BLK 512
#define D_IN 2048
#define NROWS 8192
#define NBUCKETS (NUM_BLOCKS * BLK) /* 4096 */
#define CAP 32                      /* int-ELL padded capacity (tail path) */
#define ROWS_PER_WG 8
#define THREADS 512
#define NBUK 8                      /* buckets per thread */
#define SENT 4096                   /* sentinel entry (d=2048): masked to no-op */

// Build inverted index: one WAVE per bucket. Ballot-match, ascending-d
// placement via popcount prefix. Outputs:
//  - entries16[bucket][8]: packed ushort ELL (first 8 entries, sentinel=4096)
//  - entries[bucket][CAP]: int ELL (sentinel-padded to chunk of 4) for tails
//  - nchunks[bucket]: total int4 chunks (tail runs chunks 2..nch)
__global__ __launch_bounds__(256) void cs_build_index(
    const int* __restrict__ i_hash, const float* __restrict__ s_hash,
    int* __restrict__ nchunks, int* __restrict__ entries,
    unsigned short* __restrict__ entries16)
{
    const int gid  = blockIdx.x * blockDim.x + threadIdx.x;
    const int wave = gid >> 6;            // bucket id
    const int lane = threadIdx.x & 63;
    if (wave >= NBUCKETS) return;
    const int b = wave >> 9;
    const int k = wave & (BLK - 1);
    const int*   ih = i_hash + b * D_IN;
    const float* sr = s_hash + b * D_IN;
    int* erow = entries + wave * CAP;
    unsigned short* e16 = entries16 + wave * 8;
    int cnt = 0;
    for (int d0 = 0; d0 < D_IN; d0 += 64) {
        const int d = d0 + lane;
        const bool m = (ih[d] == k);
        const unsigned long long mask = __ballot(m);
        if (m) {
            const int pos = cnt + __popcll(mask & ((1ull << lane) - 1ull));
            const int ent = (d << 1) | ((sr[d] < 0.0f) ? 1 : 0);
            if (pos < CAP) erow[pos] = ent;
            if (pos < 8)   e16[pos]  = (unsigned short)ent;
        }
        cnt += (int)__popcll(mask);
    }
    if (cnt > CAP) cnt = CAP;
    int nch = (cnt + 3) >> 2;
    if (nch == 0) nch = 1;
    if (lane >= cnt) {
        if (lane < 8)       e16[lane]  = (unsigned short)SENT;
        if (lane < nch * 4) erow[lane] = SENT;
    }
    if (lane == 0) nchunks[wave] = nch;
}

// Gather: 8 rows/WG staged transposed in LDS (xs[d][8], 64 KB exactly ->
// 2 WGs/CU). Per bucket: fixed 8-entry branch-free unroll from a single
// register-resident uint4 of packed ushort entries (loaded before the
// staging barrier -> latency hidden); each entry costs 2 ds_read_b128
// serving all 8 rows. Sentinels decode to multiplier 0 (exact fma no-op).
// Rare cnt>8 tail reads int-ELL chunks from L2. No register-held staging
// across compute (R6 spill lesson); single-buffered, one barrier.
__global__ __launch_bounds__(THREADS) void cs_gather(
    const float* __restrict__ x, const int* __restrict__ nchunks,
    const int* __restrict__ entries, const uint4* __restrict__ entries16,
    float* __restrict__ out)
{
    __shared__ float xs[D_IN][ROWS_PER_WG]; // 65536 B exactly
    const int tid  = threadIdx.x;
    const int row0 = blockIdx.x * ROWS_PER_WG;

    // Descriptor loads first: independent of LDS, hide under staging.
    uint4 e8[NBUK];
    int   nch[NBUK];
#pragma unroll
    for (int jj = 0; jj < NBUK; ++jj) {
        const int j = jj * THREADS + tid;
        e8[jj]  = entries16[j];   // coalesced 16B
        nch[jj] = nchunks[j];
    }

    // Stage transposed: thread owns d in {tid, tid+512, tid+1024, tid+1536};
    // 8 coalesced dword loads (one per row) -> 2 ds_write_b128.
    const size_t b0 = (size_t)row0 * D_IN;
#pragma unroll
    for (int i = 0; i < 4; ++i) {
        const int d = tid + i * THREADS;
        float v0 = x[b0 + d];
        float v1 = x[b0 + 1 * D_IN + d];
        float v2 = x[b0 + 2 * D_IN + d];
        float v3 = x[b0 + 3 * D_IN + d];
        float v4 = x[b0 + 4 * D_IN + d];
        float v5 = x[b0 + 5 * D_IN + d];
        float v6 = x[b0 + 6 * D_IN + d];
        float v7 = x[b0 + 7 * D_IN + d];
        *(float4*)&xs[d][0] = make_float4(v0, v1, v2, v3);
        *(float4*)&xs[d][4] = make_float4(v4, v5, v6, v7);
    }
    __syncthreads();

    const float scale = 0.35355339059327373f; // 1/sqrt(8)

    // e < 4096: real entry (d = e>>1, sign = e&1). e >= 4096: sentinel ->
    // multiplier 0.0 (fmaf(0,v,a)==a exactly for finite v).
#define PE(e)                                                             \
    do {                                                                  \
        const unsigned ue = (unsigned)(e);                                \
        const int d = (int)((ue >> 1) & 2047u);                           \
        float sg = (ue & 1u) ? -1.0f : 1.0f;                              \
        if (ue >= 4096u) sg = 0.0f;                                       \
        const float4 lo = *(const float4*)&xs[d][0];                      \
        const float4 hi = *(const float4*)&xs[d][4];                      \
        a0 = fmaf(sg, lo.x, a0); a1 = fmaf(sg, lo.y, a1);                 \
        a2 = fmaf(sg, lo.z, a2); a3 = fmaf(sg, lo.w, a3);                 \
        a4 = fmaf(sg, hi.x, a4); a5 = fmaf(sg, hi.y, a5);                 \
        a6 = fmaf(sg, hi.z, a6); a7 = fmaf(sg, hi.w, a7);                 \
    } while (0)

#pragma unroll
    for (int jj = 0; jj < NBUK; ++jj) {   // 8 buckets/thread, static idx
        const int j = jj * THREADS + tid;
        float a0 = 0.f, a1 = 0.f, a2 = 0.f, a3 = 0.f;
        float a4 = 0.f, a5 = 0.f, a6 = 0.f, a7 = 0.f;
        const uint4 ew = e8[jj];
        PE(ew.x & 0xffffu); PE(ew.x >> 16);
        PE(ew.y & 0xffffu); PE(ew.y >> 16);
        PE(ew.z & 0xffffu); PE(ew.z >> 16);
        PE(ew.w & 0xffffu); PE(ew.w >> 16);
        const int n = nch[jj];
        if (n > 2) {                       // rare (~2% of buckets)
            const int4* __restrict__ ep = (const int4*)(entries + j * CAP);
#pragma unroll 1
            for (int c = 2; c < n; ++c) {
                const int4 cc = ep[c];
                PE(cc.x); PE(cc.y); PE(cc.z); PE(cc.w);
            }
        }
        const size_t o = (size_t)row0 * NBUCKETS + j;  // coalesced NT stores
        __builtin_nontemporal_store(a0 * scale, &out[o]);
        __builtin_nontemporal_store(a1 * scale, &out[o + 1 * NBUCKETS]);
        __builtin_nontemporal_store(a2 * scale, &out[o + 2 * NBUCKETS]);
        __builtin_nontemporal_store(a3 * scale, &out[o + 3 * NBUCKETS]);
        __builtin_nontemporal_store(a4 * scale, &out[o + 4 * NBUCKETS]);
        __builtin_nontemporal_store(a5 * scale, &out[o + 5 * NBUCKETS]);
        __builtin_nontemporal_store(a6 * scale, &out[o + 6 * NBUCKETS]);
        __builtin_nontemporal_store(a7 * scale, &out[o + 7 * NBUCKETS]);
    }
#undef PE
}

extern "C" void kernel_launch(void* const* d_in, const int* in_sizes, int n_in,
                              void* d_out, int out_size, void* d_ws, size_t ws_size,
                              hipStream_t stream)
{
    const float* x      = (const float*)d_in[0];
    const float* s_hash = (const float*)d_in[1];
    const int*   i_hash = (const int*)d_in[2];
    float* out = (float*)d_out;

    // ws: nchunks[4096] (16KB) | entries[4096][32] (512KB) | entries16 (64KB)
    int* nchunks = (int*)d_ws;
    int* entries = nchunks + NBUCKETS;
    unsigned short* entries16 = (unsigned short*)(entries + NBUCKETS * CAP);

    cs_build_index<<<(NBUCKETS * 64) / 256, 256, 0, stream>>>(
        i_hash, s_hash, nchunks, entries, entries16);
    cs_gather<<<NROWS / ROWS_PER_WG, THREADS, 0, stream>>>(
        x, nchunks, entries, (const uint4*)entries16, out);
}